// Round 1
// baseline (521.566 us; speedup 1.0000x reference)
//
#include <hip/hip_runtime.h>

// RainKAN fused forward: x=[hist|static|time|emb] (219) -> KAN(219->64) -> KAN(64->1)
// Grid is uniform extended: knots t_m = -2.2 + 0.4*m, m=0..11; cubic (K=3), 8 bases.
// Closed form: u=(x+2.2)*2.5, j=floor(u) valid in [0,10], t=u-j; nonzero bases j-3..j
// with values {(1-t)^3, 3t^3-6t^2+4, -3t^3+3t^2+3t+1, t^3}/6  (verified == Cox-de-Boor).

__device__ __forceinline__ float silu_f(float x) {
    return x / (1.0f + __expf(-x));
}

__device__ __forceinline__ void bspline8(float x, float f[8]) {
    float u  = (x + 2.2f) * 2.5f;
    float fj = floorf(u);
    float t  = u - fj;
    int   j  = (int)fj;
    bool valid = (u >= 0.0f) && (u < 11.0f);   // x in [-2.2, 2.2), half-open like ref
    float t2 = t * t, t3 = t2 * t;
    float omt = 1.0f - t;
    float b0 = omt * omt * omt * (1.0f / 6.0f);
    float b1 = (3.0f * t3 - 6.0f * t2 + 4.0f) * (1.0f / 6.0f);
    float b2 = (-3.0f * t3 + 3.0f * t2 + 3.0f * t + 1.0f) * (1.0f / 6.0f);
    float b3 = t3 * (1.0f / 6.0f);
    if (!valid) { b0 = b1 = b2 = b3 = 0.0f; }
    int base = j - 3;                           // g == base+m gets b_m
#pragma unroll
    for (int g = 0; g < 8; ++g) {
        int m = g - base;
        float v = (m == 0) ? b0 : 0.0f;
        v = (m == 1) ? b1 : v;
        v = (m == 2) ? b2 : v;
        v = (m == 3) ? b3 : v;
        f[g] = v;
    }
}

__global__ __launch_bounds__(256) void kan_fused(
    const float* __restrict__ hist,    // [B,192]
    const float* __restrict__ statf,   // [B,3]
    const float* __restrict__ timef,   // [B,8]
    const int*   __restrict__ st_idx,  // [B]
    const float* __restrict__ emb,     // [120,16]
    const float* __restrict__ wb1,     // [219,64]
    const float* __restrict__ cf1,     // [219,64,8]
    const float* __restrict__ wb2,     // [64,1]
    const float* __restrict__ cf2,     // [64,1,8]
    float* __restrict__ out)           // [B]
{
    __shared__ float hbuf[4][32][64];  // 32 KB: [wave][o-within-phase][sample-lane]
    __shared__ float part[4][64];      // layer-2 partials per (o-quad, sample)

    const int tid = threadIdx.x;
    const int s   = tid & 63;                                    // sample lane
    const int w   = __builtin_amdgcn_readfirstlane(tid >> 6);    // wave id, uniform
    const int b   = blockIdx.x * 64 + s;

    // ---- layer 1: wave w handles i in [i0,i1), all 64 outputs, acc in VGPRs ----
    const int i0 = w * 55;
    const int i1 = (w == 3) ? 219 : (i0 + 55);

    float acc[64];
#pragma unroll
    for (int o = 0; o < 64; ++o) acc[o] = 0.0f;

    const float* embrow = emb + st_idx[b] * 16;

    for (int i = i0; i < i1; ++i) {
        float x;
        if (i < 192)      x = hist[b * 192 + i];
        else if (i < 195) x = statf[b * 3 + (i - 192)];
        else if (i < 203) x = timef[b * 8 + (i - 195)];
        else              x = embrow[i - 203];

        float sv = silu_f(x);
        float f[8];
        bspline8(x, f);

        const float* wbp = wb1 + i * 64;        // uniform address -> s_load
        const float* cfp = cf1 + i * 512;       // uniform address -> s_load
#pragma unroll
        for (int o = 0; o < 64; ++o) {
            float a = acc[o];
            a = fmaf(sv, wbp[o], a);
#pragma unroll
            for (int g = 0; g < 8; ++g)
                a = fmaf(f[g], cfp[o * 8 + g], a);
            acc[o] = a;
        }
    }

    // ---- reduce partial h across waves (2 phases of 32 outputs) + fused layer 2 ----
    float psum = 0.0f;
#pragma unroll
    for (int ph = 0; ph < 2; ++ph) {
        __syncthreads();
#pragma unroll
        for (int oo = 0; oo < 32; ++oo)
            hbuf[w][oo][s] = acc[ph * 32 + oo];   // stride-1 across lanes: no conflicts
        __syncthreads();
        if ((w >> 1) == ph) {                      // quads {0,1} do ph0, {2,3} do ph1
            const int qloc = w & 1;
#pragma unroll
            for (int oo = 0; oo < 16; ++oo) {
                const int ol = qloc * 16 + oo;     // 0..31 within phase
                const int o  = ph * 32 + ol;       // global output idx, uniform
                float h = hbuf[0][ol][s] + hbuf[1][ol][s] + hbuf[2][ol][s] + hbuf[3][ol][s];
                psum = fmaf(silu_f(h), wb2[o], psum);
                float f2[8];
                bspline8(h, f2);
                const float* c2 = cf2 + o * 8;     // uniform -> s_load
#pragma unroll
                for (int g = 0; g < 8; ++g)
                    psum = fmaf(f2[g], c2[g], psum);
            }
        }
    }

    part[w][s] = psum;
    __syncthreads();
    if (tid < 64)
        out[blockIdx.x * 64 + tid] =
            part[0][tid] + part[1][tid] + part[2][tid] + part[3][tid];
}

extern "C" void kernel_launch(void* const* d_in, const int* in_sizes, int n_in,
                              void* d_out, int out_size, void* d_ws, size_t ws_size,
                              hipStream_t stream) {
    const float* hist  = (const float*)d_in[0];
    const float* statf = (const float*)d_in[1];
    const float* timef = (const float*)d_in[2];
    const int*   stidx = (const int*)  d_in[3];
    const float* emb   = (const float*)d_in[4];
    const float* wb1   = (const float*)d_in[5];
    const float* cf1   = (const float*)d_in[6];
    const float* wb2   = (const float*)d_in[7];
    const float* cf2   = (const float*)d_in[8];
    float* out = (float*)d_out;

    kan_fused<<<256, 256, 0, stream>>>(hist, statf, timef, stidx, emb,
                                       wb1, cf1, wb2, cf2, out);
}

// Round 2
// 131.463 us; speedup vs baseline: 3.9674x; 3.9674x over previous
//
#include <hip/hip_runtime.h>

// RainKAN fused forward via MFMA f16:
//   X[B, K=3584] (per-input 16 slots: silu, 8 cubic-spline bases, 7 zero) x W[K,64]
//   -> h[B,64] -> exact fp32 KAN layer 2 -> out[B]
// Grid: uniform knots t_m = -2.2 + 0.4m; closed-form cubic B-spline 4-tap.
// W is prepped each launch into d_ws as fp16, pre-swizzled in MFMA B-fragment
// order: frag element (q, nt, lane, j) = W[k = q*32 + (lane>>4)*8 + j][n = nt*16 + (lane&15)].

typedef _Float16 half8 __attribute__((ext_vector_type(8)));
typedef float floatx4 __attribute__((ext_vector_type(4)));

#define KPAD   3584          // 224 i-slots * 16
#define NSTEPS 112           // 3584 / 32 MFMA K-steps
#define NTILES 14            // 3584 / 256
#define FROW   264           // feat row stride in halves (256 + 8 pad)

__device__ __forceinline__ float silu_f(float x) {
    return x / (1.0f + __expf(-x));
}

__device__ __forceinline__ void bspline8(float x, float f[8]) {
    float u  = (x + 2.2f) * 2.5f;
    float fj = floorf(u);
    float t  = u - fj;
    int   j  = (int)fj;
    bool valid = (u >= 0.0f) && (u < 11.0f);   // x in [-2.2, 2.2), half-open like ref
    float t2 = t * t, t3 = t2 * t;
    float omt = 1.0f - t;
    float b0 = omt * omt * omt * (1.0f / 6.0f);
    float b1 = (3.0f * t3 - 6.0f * t2 + 4.0f) * (1.0f / 6.0f);
    float b2 = (-3.0f * t3 + 3.0f * t2 + 3.0f * t + 1.0f) * (1.0f / 6.0f);
    float b3 = t3 * (1.0f / 6.0f);
    if (!valid) { b0 = b1 = b2 = b3 = 0.0f; }
    int base = j - 3;
#pragma unroll
    for (int g = 0; g < 8; ++g) {
        int m = g - base;
        float v = (m == 0) ? b0 : 0.0f;
        v = (m == 1) ? b1 : v;
        v = (m == 2) ? b2 : v;
        v = (m == 3) ? b3 : v;
        f[g] = v;
    }
}

// ---- prep: wb1[219,64] + cf1[219,64,8] -> fp16 B-fragment-swizzled wcat[229376] ----
__global__ __launch_bounds__(256) void build_w(
    const float* __restrict__ wb1, const float* __restrict__ cf1,
    _Float16* __restrict__ wcat)
{
    int flat = blockIdx.x * 256 + threadIdx.x;      // < 229376
    int j   = flat & 7;
    int l   = (flat >> 3) & 63;
    int qnt = flat >> 9;
    int nt  = qnt & 3;
    int q   = qnt >> 2;                             // 0..111
    int k   = q * 32 + ((l >> 4) << 3) + j;         // 0..3583
    int n   = nt * 16 + (l & 15);
    int i   = k >> 4;
    int g   = k & 15;
    float v = 0.0f;
    if (i < 219) {
        if (g == 0)      v = wb1[i * 64 + n];
        else if (g <= 8) v = cf1[(i * 64 + n) * 8 + (g - 1)];
    }
    wcat[flat] = (_Float16)v;
}

// ---- fused GEMM + layer 2: 256 blocks x 256 threads, 64 samples/block ----
__global__ __launch_bounds__(256) void kan_mfma(
    const float* __restrict__ hist,    // [B,192]
    const float* __restrict__ statf,   // [B,3]
    const float* __restrict__ timef,   // [B,8]
    const int*   __restrict__ st_idx,  // [B]
    const float* __restrict__ emb,     // [120,16]
    const _Float16* __restrict__ wcat, // [229376] B-fragment order
    const float* __restrict__ wb2,     // [64]
    const float* __restrict__ cf2,     // [64,8]
    float* __restrict__ out)           // [B]
{
    __shared__ union {
        _Float16 feat[64 * FROW];                       // 33792 B
        struct { float h[64 * 65]; float part[4 * 64]; } ep;  // 17664 B
    } sm;

    const int tid  = threadIdx.x;
    const int lane = tid & 63;
    const int w    = __builtin_amdgcn_readfirstlane(tid >> 6);  // wave id (= n-tile)
    const int bx   = blockIdx.x;
    const int b    = bx * 64 + lane;                     // this thread's sample row

    const float* embrow = emb + st_idx[b] * 16;

    floatx4 acc[4];
#pragma unroll
    for (int mt = 0; mt < 4; ++mt) acc[mt] = (floatx4){0.f, 0.f, 0.f, 0.f};

    for (int t = 0; t < NTILES; ++t) {
        __syncthreads();   // previous tile's MFMA reads done before overwrite
        // --- feature gen: this thread fills feat[lane][iloc*16..+16] for 4 i's ---
#pragma unroll
        for (int r = 0; r < 4; ++r) {
            const int iloc = w + 4 * r;                  // wave-uniform, 0..15
            const int i    = t * 16 + iloc;
            _Float16 fv[16];
#pragma unroll
            for (int z = 0; z < 16; ++z) fv[z] = (_Float16)0.0f;
            if (i < 219) {
                float x;
                if (i < 192)      x = hist[b * 192 + i];
                else if (i < 195) x = statf[b * 3 + (i - 192)];
                else if (i < 203) x = timef[b * 8 + (i - 195)];
                else              x = embrow[i - 203];
                fv[0] = (_Float16)silu_f(x);
                float f[8];
                bspline8(x, f);
#pragma unroll
                for (int g = 0; g < 8; ++g) fv[1 + g] = (_Float16)f[g];
            }
            half8* dst = (half8*)&sm.feat[lane * FROW + iloc * 16];
            dst[0] = *(half8*)&fv[0];
            dst[1] = *(half8*)&fv[8];
        }
        __syncthreads();
        // --- MFMA: 8 K-steps over this tile; wave owns n-tile w ---
#pragma unroll
        for (int qq = 0; qq < 8; ++qq) {
            const int q = t * 8 + qq;                    // global K-step
            half8 bfrag = *(const half8*)(wcat + (size_t)((q * 4 + w) * 64 + lane) * 8);
            const int koff = qq * 32 + ((lane >> 4) << 3);
#pragma unroll
            for (int mt = 0; mt < 4; ++mt) {
                half8 afrag = *(const half8*)&sm.feat[(mt * 16 + (lane & 15)) * FROW + koff];
                acc[mt] = __builtin_amdgcn_mfma_f32_16x16x32_f16(afrag, bfrag, acc[mt], 0, 0, 0);
            }
        }
    }

    __syncthreads();   // MFMA reads of feat done; reuse LDS for epilogue
    // C/D layout: col = lane&15 (n within tile), row = (lane>>4)*4 + reg (m within tile)
#pragma unroll
    for (int mt = 0; mt < 4; ++mt) {
#pragma unroll
        for (int r = 0; r < 4; ++r) {
            const int row = mt * 16 + ((lane >> 4) << 2) + r;
            const int col = w * 16 + (lane & 15);
            sm.ep.h[row * 65 + col] = acc[mt][r];
        }
    }
    __syncthreads();

    // --- exact fp32 layer 2: thread (w, lane): sample=lane, outputs w*16..+16 ---
    float psum = 0.0f;
#pragma unroll
    for (int oo = 0; oo < 16; ++oo) {
        const int o = w * 16 + oo;                       // wave-uniform
        float h = sm.ep.h[lane * 65 + o];
        psum = fmaf(silu_f(h), wb2[o], psum);
        float f2[8];
        bspline8(h, f2);
#pragma unroll
        for (int g = 0; g < 8; ++g)
            psum = fmaf(f2[g], cf2[o * 8 + g], psum);
    }
    sm.ep.part[w * 64 + lane] = psum;
    __syncthreads();
    if (tid < 64)
        out[bx * 64 + tid] = sm.ep.part[tid] + sm.ep.part[64 + tid] +
                             sm.ep.part[128 + tid] + sm.ep.part[192 + tid];
}

extern "C" void kernel_launch(void* const* d_in, const int* in_sizes, int n_in,
                              void* d_out, int out_size, void* d_ws, size_t ws_size,
                              hipStream_t stream) {
    const float* hist  = (const float*)d_in[0];
    const float* statf = (const float*)d_in[1];
    const float* timef = (const float*)d_in[2];
    const int*   stidx = (const int*)  d_in[3];
    const float* emb   = (const float*)d_in[4];
    const float* wb1   = (const float*)d_in[5];
    const float* cf1   = (const float*)d_in[6];
    const float* wb2   = (const float*)d_in[7];
    const float* cf2   = (const float*)d_in[8];
    float* out = (float*)d_out;

    _Float16* wcat = (_Float16*)d_ws;   // 229376 fp16 = 458752 B

    build_w<<<896, 256, 0, stream>>>(wb1, cf1, wcat);
    kan_mfma<<<256, 256, 0, stream>>>(hist, statf, timef, stidx, emb,
                                      wcat, wb2, cf2, out);
}

// Round 3
// 110.372 us; speedup vs baseline: 4.7255x; 1.1911x over previous
//
#include <hip/hip_runtime.h>

// RainKAN fused forward via MFMA f16, packed K.
//   X[B, K=2016] x W[K,64] -> h[B,64] -> exact fp32 KAN layer 2 -> out[B]
// K-order: 7 input-blocks of 32 inputs; per block: [32 silu slots][32x8 spline slots]
// (288 halves = 9 MFMA K-steps). GEMM sums over k, so any K-order is valid as long
// as W (built by build_w into d_ws, fp16, B-fragment order) uses the same order.
// B-frag element (step, nt, lane, j) = W[k_local = (step%9)*32+(lane>>4)*8+j of
// input-block step/9][n = nt*16 + (lane&15)].
// Spline grid: uniform knots t_m = -2.2+0.4m; closed-form cubic 4-tap.

typedef _Float16 half8 __attribute__((ext_vector_type(8)));
typedef float floatx4 __attribute__((ext_vector_type(4)));

#define NTILES 7            // input-blocks of 32 (219 -> 224)
#define QSTEPS 9            // K-steps per input-block (288/32)
#define FROW   296          // feat row stride in halves (288 + 8 pad)

__device__ __forceinline__ float silu_f(float x) {
    return x / (1.0f + __expf(-x));
}

__device__ __forceinline__ void bspline8(float x, float f[8]) {
    float u  = (x + 2.2f) * 2.5f;
    float fj = floorf(u);
    float t  = u - fj;
    int   j  = (int)fj;
    bool valid = (u >= 0.0f) && (u < 11.0f);   // x in [-2.2, 2.2), half-open like ref
    float t2 = t * t, t3 = t2 * t;
    float omt = 1.0f - t;
    float b0 = omt * omt * omt * (1.0f / 6.0f);
    float b1 = (3.0f * t3 - 6.0f * t2 + 4.0f) * (1.0f / 6.0f);
    float b2 = (-3.0f * t3 + 3.0f * t2 + 3.0f * t + 1.0f) * (1.0f / 6.0f);
    float b3 = t3 * (1.0f / 6.0f);
    if (!valid) { b0 = b1 = b2 = b3 = 0.0f; }
    int base = j - 3;
#pragma unroll
    for (int g = 0; g < 8; ++g) {
        int m = g - base;
        float v = (m == 0) ? b0 : 0.0f;
        v = (m == 1) ? b1 : v;
        v = (m == 2) ? b2 : v;
        v = (m == 3) ? b3 : v;
        f[g] = v;
    }
}

// ---- prep: wb1[219,64] + cf1[219,64,8] -> fp16 B-frag-swizzled wcat[129024] ----
__global__ __launch_bounds__(256) void build_w(
    const float* __restrict__ wb1, const float* __restrict__ cf1,
    _Float16* __restrict__ wcat)
{
    int flat = blockIdx.x * 256 + threadIdx.x;      // < 63*4*512 = 129024
    int j    = flat & 7;
    int l    = (flat >> 3) & 63;
    int nt   = (flat >> 9) & 3;
    int step = flat >> 11;                          // 0..62
    int t    = step / QSTEPS;                       // input-block 0..6
    int q    = step - t * QSTEPS;                   // 0..8
    int kl   = q * 32 + ((l >> 4) << 3) + j;        // 0..287 within block
    int n    = nt * 16 + (l & 15);
    float v  = 0.0f;
    if (kl < 32) {                                  // silu segment
        int i = t * 32 + kl;
        if (i < 219) v = wb1[i * 64 + n];
    } else {                                        // spline segment
        int sp = kl - 32;
        int i  = t * 32 + (sp >> 3);
        int g  = sp & 7;
        if (i < 219) v = cf1[(i * 64 + n) * 8 + g];
    }
    wcat[flat] = (_Float16)v;
}

// ---- fused GEMM + layer 2: 512 blocks x 256 threads, 32 samples/block ----
__global__ __launch_bounds__(256) void kan_mfma(
    const float* __restrict__ hist,    // [B,192]
    const float* __restrict__ statf,   // [B,3]
    const float* __restrict__ timef,   // [B,8]
    const int*   __restrict__ st_idx,  // [B]
    const float* __restrict__ emb,     // [120,16]
    const _Float16* __restrict__ wcat, // [129024] B-fragment order
    const float* __restrict__ wb2,     // [64]
    const float* __restrict__ cf2,     // [64,8]
    float* __restrict__ out)           // [B]
{
    __shared__ union {
        _Float16 feat[32 * FROW];                             // 18944 B
        struct { float h[32 * 65]; float part[8 * 32]; } ep;  // 9344 B
    } sm;

    const int tid  = threadIdx.x;
    const int lane = tid & 63;
    const int w    = __builtin_amdgcn_readfirstlane(tid >> 6);  // wave id = n-tile
    const int bx   = blockIdx.x;

    // feature-gen thread map: lane&31 = input-within-block (coalesced), rest = sample
    const int iloc = tid & 31;
    const int sg   = tid >> 5;          // 0..7; sample s = sg*4 + r

    floatx4 acc[2];
    acc[0] = (floatx4){0.f, 0.f, 0.f, 0.f};
    acc[1] = (floatx4){0.f, 0.f, 0.f, 0.f};

    for (int t = 0; t < NTILES; ++t) {
        const int i = t * 32 + iloc;
        __syncthreads();                 // prior tile's MFMA reads done
#pragma unroll
        for (int r = 0; r < 4; ++r) {
            const int s = sg * 4 + r;
            const int b = bx * 32 + s;
            float sv = 0.0f;
            half8 spl = (half8)(_Float16)0.0f;
            if (i < 219) {
                float x;
                if (i < 192)      x = hist[b * 192 + i];           // coalesced
                else if (i < 195) x = statf[b * 3 + (i - 192)];
                else if (i < 203) x = timef[b * 8 + (i - 195)];
                else              x = emb[st_idx[b] * 16 + (i - 203)];
                sv = silu_f(x);
                float f[8];
                bspline8(x, f);
#pragma unroll
                for (int g = 0; g < 8; ++g) spl[g] = (_Float16)f[g];
            }
            sm.feat[s * FROW + iloc] = (_Float16)sv;
            *(half8*)&sm.feat[s * FROW + 32 + iloc * 8] = spl;
        }
        __syncthreads();
        // MFMA: 9 K-steps; wave owns n-tile w; 2 m-tiles of 16 samples
#pragma unroll
        for (int q = 0; q < QSTEPS; ++q) {
            half8 bfrag = *(const half8*)(wcat + (size_t)(((t * QSTEPS + q) * 4 + w) * 64 + lane) * 8);
            const int koff = q * 32 + ((lane >> 4) << 3);
#pragma unroll
            for (int mt = 0; mt < 2; ++mt) {
                half8 afrag = *(const half8*)&sm.feat[(mt * 16 + (lane & 15)) * FROW + koff];
                acc[mt] = __builtin_amdgcn_mfma_f32_16x16x32_f16(afrag, bfrag, acc[mt], 0, 0, 0);
            }
        }
    }

    __syncthreads();   // MFMA done; reuse LDS for epilogue
    // C/D layout: col = lane&15, row = (lane>>4)*4 + reg
#pragma unroll
    for (int mt = 0; mt < 2; ++mt) {
#pragma unroll
        for (int r = 0; r < 4; ++r) {
            const int row = mt * 16 + ((lane >> 4) << 2) + r;
            const int col = w * 16 + (lane & 15);
            sm.ep.h[row * 65 + col] = acc[mt][r];
        }
    }
    __syncthreads();

    // exact fp32 layer 2: thread (s = tid&31, og = tid>>5) does outputs og*8..+8
    {
        const int s  = tid & 31;
        const int og = tid >> 5;
        float psum = 0.0f;
#pragma unroll
        for (int oo = 0; oo < 8; ++oo) {
            const int o = og * 8 + oo;
            float h = sm.ep.h[s * 65 + o];
            psum = fmaf(silu_f(h), wb2[o], psum);
            float f2[8];
            bspline8(h, f2);
#pragma unroll
            for (int g = 0; g < 8; ++g)
                psum = fmaf(f2[g], cf2[o * 8 + g], psum);
        }
        sm.ep.part[og * 32 + s] = psum;
    }
    __syncthreads();
    if (tid < 32) {
        float r = 0.0f;
#pragma unroll
        for (int og = 0; og < 8; ++og) r += sm.ep.part[og * 32 + tid];
        out[bx * 32 + tid] = r;
    }
}

extern "C" void kernel_launch(void* const* d_in, const int* in_sizes, int n_in,
                              void* d_out, int out_size, void* d_ws, size_t ws_size,
                              hipStream_t stream) {
    const float* hist  = (const float*)d_in[0];
    const float* statf = (const float*)d_in[1];
    const float* timef = (const float*)d_in[2];
    const int*   stidx = (const int*)  d_in[3];
    const float* emb   = (const float*)d_in[4];
    const float* wb1   = (const float*)d_in[5];
    const float* cf1   = (const float*)d_in[6];
    const float* wb2   = (const float*)d_in[7];
    const float* cf2   = (const float*)d_in[8];
    float* out = (float*)d_out;

    _Float16* wcat = (_Float16*)d_ws;   // 129024 fp16 = 258048 B

    build_w<<<504, 256, 0, stream>>>(wb1, cf1, wcat);
    kan_mfma<<<512, 256, 0, stream>>>(hist, statf, timef, stidx, emb,
                                      wcat, wb2, cf2, out);
}

// Round 4
// 94.082 us; speedup vs baseline: 5.5437x; 1.1731x over previous
//
#include <hip/hip_runtime.h>

// RainKAN fused forward via MFMA f16, register-built A-fragments.
//   X[B, K=2016] x W[K,64] -> h[B,64] -> exact fp32 KAN layer 2 -> out[B]
// K-order: steps 0..62 (32 k each). Steps 0..6: silu slots, k = st*32+kg*8+j -> input i=k.
// Steps 7..62: spline slots, input i = (st-7)*4 + kg, basis g = j.
// A-frag (16x16x32 f16): lane(m=lane&15, kg=lane>>4) holds k = kg*8+j -> for a spline
// step that's all 8 bases of ONE x -> built in registers from one LDS x-read. No feat LDS.
// W prepped into d_ws fp16 B-frag order: element(st,nt,lane,j) = W[st*32+kg*8+j][nt*16+(lane&15)].
// Spline grid: uniform knots t_m = -2.2+0.4m; closed-form cubic 4-tap, placed via
// 128-bit funnel shift by (j-3)*16 bits (drops out-of-range bases correctly).

typedef _Float16 half8 __attribute__((ext_vector_type(8)));
typedef float floatx4 __attribute__((ext_vector_type(4)));

#define XR 233   // x-row stride in floats (odd -> 2-way max LDS conflicts on reads)

__device__ __forceinline__ float silu_f(float x) {
    return x / (1.0f + __expf(-x));
}

// fp32 dense bases (exact layer-2 path)
__device__ __forceinline__ void bspline8_dense(float x, float f[8]) {
    float u  = (x + 2.2f) * 2.5f;
    float fj = floorf(u);
    float t  = u - fj;
    int   j  = (int)fj;
    bool valid = (u >= 0.0f) && (u < 11.0f);
    float t2 = t * t, t3 = t2 * t, omt = 1.0f - t;
    float b0 = omt * omt * omt * (1.0f / 6.0f);
    float b1 = (3.0f * t3 - 6.0f * t2 + 4.0f) * (1.0f / 6.0f);
    float b2 = (-3.0f * t3 + 3.0f * t2 + 3.0f * t + 1.0f) * (1.0f / 6.0f);
    float b3 = t3 * (1.0f / 6.0f);
    if (!valid) { b0 = b1 = b2 = b3 = 0.0f; }
    int base = j - 3;
#pragma unroll
    for (int g = 0; g < 8; ++g) {
        int m = g - base;
        float v = (m == 0) ? b0 : 0.0f;
        v = (m == 1) ? b1 : v;
        v = (m == 2) ? b2 : v;
        v = (m == 3) ? b3 : v;
        f[g] = v;
    }
}

// f16 A-fragment: 8 bases placed at slots (j-3)..j via 128-bit shift
__device__ __forceinline__ half8 bspline_frag(float x) {
    float u  = (x + 2.2f) * 2.5f;
    float fj = floorf(u);
    float t  = u - fj;
    int   j  = (int)fj;
    bool valid = (u >= 0.0f) && (u < 11.0f);
    float t2 = t * t, t3 = t2 * t, omt = 1.0f - t;
    float b0 = omt * omt * omt * (1.0f / 6.0f);
    float b1 = (3.0f * t3 - 6.0f * t2 + 4.0f) * (1.0f / 6.0f);
    float b2 = (-3.0f * t3 + 3.0f * t2 + 3.0f * t + 1.0f) * (1.0f / 6.0f);
    float b3 = t3 * (1.0f / 6.0f);
    union { _Float16 h[4]; unsigned long long q; } p;
    p.h[0] = (_Float16)b0; p.h[1] = (_Float16)b1;
    p.h[2] = (_Float16)b2; p.h[3] = (_Float16)b3;
    unsigned long long lo = valid ? p.q : 0ull;
    int jc = valid ? j : 3;              // keep shift amounts in defined range
    int sh = (jc - 3) * 16;              // bits, in [-48, 112]
    unsigned long long rlo, rhi;
    if (sh >= 0) {
        rlo = (sh < 64) ? (lo << sh) : 0ull;
        rhi = (sh == 0) ? 0ull
            : (sh < 64) ? (lo >> (64 - sh))
                        : (lo << (sh - 64));
    } else {
        rlo = lo >> (-sh);
        rhi = 0ull;
    }
    union { unsigned long long q[2]; half8 v; } r;
    r.q[0] = rlo; r.q[1] = rhi;
    return r.v;
}

// ---- prep: wb1[219,64] + cf1[219,64,8] -> fp16 B-frag wcat[129024] (258 KB) ----
__global__ __launch_bounds__(256) void build_w(
    const float* __restrict__ wb1, const float* __restrict__ cf1,
    _Float16* __restrict__ wcat)
{
    int flat = blockIdx.x * 256 + threadIdx.x;   // < 63*4*64 = 16128
    int lane = flat & 63;
    int nt   = (flat >> 6) & 3;
    int st   = flat >> 8;                        // 0..62
    int kg   = lane >> 4;
    int n    = nt * 16 + (lane & 15);
    _Float16 v[8];
    if (st < 7) {
#pragma unroll
        for (int j = 0; j < 8; ++j) {
            int i = st * 32 + kg * 8 + j;
            v[j] = (_Float16)((i < 219) ? wb1[i * 64 + n] : 0.0f);
        }
    } else {
        int i = (st - 7) * 4 + kg;
#pragma unroll
        for (int j = 0; j < 8; ++j)
            v[j] = (_Float16)((i < 219) ? cf1[(i * 64 + n) * 8 + j] : 0.0f);
    }
    *(half8*)(wcat + (size_t)flat * 8) = *(half8*)v;
}

// ---- fused GEMM + layer 2: 512 blocks x 256 threads, 32 samples/block ----
// wave w: m-tile = w&1 (16 samples), K-parity = w>>1; all 4 n-tiles per wave.
__global__ __launch_bounds__(256) void kan_mfma(
    const float* __restrict__ hist,    // [B,192]
    const float* __restrict__ statf,   // [B,3]
    const float* __restrict__ timef,   // [B,8]
    const int*   __restrict__ st_idx,  // [B]
    const float* __restrict__ emb,     // [120,16]
    const _Float16* __restrict__ wcat, // [129024]
    const float* __restrict__ wb2,     // [64]
    const float* __restrict__ cf2,     // [64,8]
    float* __restrict__ out)           // [B]
{
    __shared__ union {
        float xb[32 * XR];                                      // 29824 B
        struct { float h[2][32 * 65]; float part[8 * 32]; } ep; // 17664 B
    } sm;

    const int tid  = threadIdx.x;
    const int lane = tid & 63;
    const int w    = __builtin_amdgcn_readfirstlane(tid >> 6);
    const int mt   = w & 1;
    const int kh   = w >> 1;
    const int bx   = blockIdx.x;
    const int row  = lane & 15;
    const int kg   = lane >> 4;

    // ---- stage raw x[32][224] into LDS, coalesced ----
    {
        const int s = tid >> 3, q4 = tid & 7;
        const int b = bx * 32 + s;
        const float4* h4 = (const float4*)hist;   // hist rows: 48 float4
#pragma unroll
        for (int f = 0; f < 6; ++f) {
            int i4 = q4 + 8 * f;                  // 0..47
            float4 v = h4[b * 48 + i4];
            sm.xb[s * XR + i4 * 4 + 0] = v.x;
            sm.xb[s * XR + i4 * 4 + 1] = v.y;
            sm.xb[s * XR + i4 * 4 + 2] = v.z;
            sm.xb[s * XR + i4 * 4 + 3] = v.w;
        }
    }
#pragma unroll
    for (int f = 0; f < 4; ++f) {
        int flat = f * 256 + tid;
        int s  = flat >> 5;
        int ii = 192 + (flat & 31);               // 192..223
        int b  = bx * 32 + s;
        float v;
        if (ii < 195)      v = statf[b * 3 + (ii - 192)];
        else if (ii < 203) v = timef[b * 8 + (ii - 195)];
        else if (ii < 219) v = emb[st_idx[b] * 16 + (ii - 203)];
        else               v = 0.0f;
        sm.xb[s * XR + ii] = v;
    }
    __syncthreads();

    const float* xrow = &sm.xb[(mt * 16 + row) * XR];

    floatx4 acc[4];
#pragma unroll
    for (int nt = 0; nt < 4; ++nt) acc[nt] = (floatx4){0.f, 0.f, 0.f, 0.f};

    // ---- silu steps (st = kh, kh+2, ... < 7) ----
    for (int st = kh; st < 7; st += 2) {
        const _Float16* wp = wcat + (size_t)(st * 4) * 512 + lane * 8;
        half8 bf0 = *(const half8*)(wp);
        half8 bf1 = *(const half8*)(wp + 512);
        half8 bf2 = *(const half8*)(wp + 1024);
        half8 bf3 = *(const half8*)(wp + 1536);
        const int i0 = st * 32 + kg * 8;
        half8 af;
#pragma unroll
        for (int jj = 0; jj < 8; ++jj)
            af[jj] = (_Float16)silu_f(xrow[i0 + jj]);
        acc[0] = __builtin_amdgcn_mfma_f32_16x16x32_f16(af, bf0, acc[0], 0, 0, 0);
        acc[1] = __builtin_amdgcn_mfma_f32_16x16x32_f16(af, bf1, acc[1], 0, 0, 0);
        acc[2] = __builtin_amdgcn_mfma_f32_16x16x32_f16(af, bf2, acc[2], 0, 0, 0);
        acc[3] = __builtin_amdgcn_mfma_f32_16x16x32_f16(af, bf3, acc[3], 0, 0, 0);
    }

    // ---- spline steps (st >= 7, parity kh) ----
    const int st0 = (kh == 1) ? 7 : 8;
#pragma unroll 2
    for (int st = st0; st < 63; st += 2) {
        const _Float16* wp = wcat + (size_t)(st * 4) * 512 + lane * 8;
        half8 bf0 = *(const half8*)(wp);
        half8 bf1 = *(const half8*)(wp + 512);
        half8 bf2 = *(const half8*)(wp + 1024);
        half8 bf3 = *(const half8*)(wp + 1536);
        float x = xrow[(st - 7) * 4 + kg];
        half8 af = bspline_frag(x);
        acc[0] = __builtin_amdgcn_mfma_f32_16x16x32_f16(af, bf0, acc[0], 0, 0, 0);
        acc[1] = __builtin_amdgcn_mfma_f32_16x16x32_f16(af, bf1, acc[1], 0, 0, 0);
        acc[2] = __builtin_amdgcn_mfma_f32_16x16x32_f16(af, bf2, acc[2], 0, 0, 0);
        acc[3] = __builtin_amdgcn_mfma_f32_16x16x32_f16(af, bf3, acc[3], 0, 0, 0);
    }

    // ---- epilogue: h partials to LDS (C/D: col=lane&15, row=(lane>>4)*4+reg) ----
    __syncthreads();   // all waves done reading xb before overwrite
#pragma unroll
    for (int nt = 0; nt < 4; ++nt) {
#pragma unroll
        for (int r = 0; r < 4; ++r) {
            const int rr = mt * 16 + kg * 4 + r;
            const int cc = nt * 16 + row;
            sm.ep.h[kh][rr * 65 + cc] = acc[nt][r];
        }
    }
    __syncthreads();

    // ---- exact fp32 layer 2 ----
    {
        const int s  = tid & 31;
        const int og = tid >> 5;
        float psum = 0.0f;
#pragma unroll
        for (int oo = 0; oo < 8; ++oo) {
            const int o = og * 8 + oo;
            float h = sm.ep.h[0][s * 65 + o] + sm.ep.h[1][s * 65 + o];
            psum = fmaf(silu_f(h), wb2[o], psum);
            float f2[8];
            bspline8_dense(h, f2);
#pragma unroll
            for (int g = 0; g < 8; ++g)
                psum = fmaf(f2[g], cf2[o * 8 + g], psum);
        }
        sm.ep.part[og * 32 + s] = psum;
    }
    __syncthreads();
    if (tid < 32) {
        float r = 0.0f;
#pragma unroll
        for (int og = 0; og < 8; ++og) r += sm.ep.part[og * 32 + tid];
        out[bx * 32 + tid] = r;
    }
}

extern "C" void kernel_launch(void* const* d_in, const int* in_sizes, int n_in,
                              void* d_out, int out_size, void* d_ws, size_t ws_size,
                              hipStream_t stream) {
    const float* hist  = (const float*)d_in[0];
    const float* statf = (const float*)d_in[1];
    const float* timef = (const float*)d_in[2];
    const int*   stidx = (const int*)  d_in[3];
    const float* emb   = (const float*)d_in[4];
    const float* wb1   = (const float*)d_in[5];
    const float* cf1   = (const float*)d_in[6];
    const float* wb2   = (const float*)d_in[7];
    const float* cf2   = (const float*)d_in[8];
    float* out = (float*)d_out;

    _Float16* wcat = (_Float16*)d_ws;   // 129024 fp16 = 258 KB

    build_w<<<63, 256, 0, stream>>>(wb1, cf1, wcat);
    kan_mfma<<<512, 256, 0, stream>>>(hist, statf, timef, stidx, emb,
                                      wcat, wb2, cf2, out);
}